// Round 3
// baseline (283.871 us; speedup 1.0000x reference)
//
#include <hip/hip_runtime.h>

// B=4, N=8, C=256, H=64, W=64, D=512 (single query per batch).
// Algebraic collapse: c is the only large tensor; K and V never formed.
//   gqk[b,c]  = g[c] * D^-0.5 * (Wkv_upper^T (Wq q_b))[c]
//   d[n,px]   = invr[n,px] * <c[b,n,:,px], gqk[b,:]>
//   w[n,px]   = softmax_n(d) * invr[n,px]
//   t[c,px]   = sum_n w[n,px] * c[b,n,c,px]
//   out       = Wovg @ t + bo,  Wovg = Wo @ Wkv_lower * diag(g)  (bf16 MFMA)
//
// R5: R4's passes ran at ~3.5 TB/s because scalar lanes -> 256 B DRAM spans
// (page-activation-bound; R2's 128 B spans gave 2.33 TB/s). Every c-touching
// pass now loads float4 per lane: 1 KB contiguous per wave instruction,
// 4 KB per block per 16 KB channel row.
//   stats1: (b,n,1024px,64ch-quarter) blocks, partial (ssq,dt) -> 4 MB
//   stats2: combine + exact softmax -> final weights w[b][px][n] (512 KB)
//   wsum  : (b,8ch,1024px) blocks, t[8ch][4px] in regs (~85 VGPR, static
//           indexing), bf16 B-fragment stores (64 B/thread contiguous)
//   gemm  : out = Wovg @ t + bo via 16x16x32 bf16 MFMA (unchanged)
// ws: [0,131072)          WovgB bf16, A-fragment-linear:
//                         (i,c) -> ((((i>>4)*8+(c>>5))*4+((c>>3)&3))*16+(i&15))*8+(c&7)
//     [131072,135168)     gqk f32 [4][256]
//     [135168,4329472)    partials float2 [4 b][8 n][4 chs][4096 px] = (ssq,dt)
//     [4329472,4853760)   w f32 [4 b][4096 px][8 n]
//     [4853760,13242368)  tfrag bf16: (b,P=px>>4,s,q,m=px&15,jj) ->
//                         short idx ((((b*256+P)*8+s)*4+q)*16+m)*8+jj

typedef __attribute__((ext_vector_type(8))) short short8;
typedef __attribute__((ext_vector_type(4))) float floatx4;

static __device__ __forceinline__ short f2bf(float f) {
  unsigned u = __float_as_uint(f);
  u += 0x7fffu + ((u >> 16) & 1u);   // round-to-nearest-even
  return (short)(u >> 16);
}

// blocks 0..63: Wovg rows 4i..4i+3 (Wkv_lower stays L2-hot across blocks)
// blocks 64..67: gqk for batch b
__global__ __launch_bounds__(256) void pre_kernel(
    const float* __restrict__ q, const float* __restrict__ g,
    const float* __restrict__ Wq, const float* __restrict__ Wkv,
    const float* __restrict__ Wo, unsigned char* __restrict__ ws) {
  short* WovgB = (short*)ws;
  float* gqk = (float*)(ws + 131072);
  const int blk = blockIdx.x, tid = threadIdx.x;
  if (blk < 64) {
    const int i0 = blk * 4, c = tid;
    float s0 = 0.f, s1 = 0.f, s2 = 0.f, s3 = 0.f;
    #pragma unroll 8
    for (int d = 0; d < 512; ++d) {
      const float wv = Wkv[(512 + d) * 256 + c];   // vector load
      s0 = fmaf(Wo[(i0 + 0) * 512 + d], wv, s0);   // Wo: uniform -> s_load
      s1 = fmaf(Wo[(i0 + 1) * 512 + d], wv, s1);
      s2 = fmaf(Wo[(i0 + 2) * 512 + d], wv, s2);
      s3 = fmaf(Wo[(i0 + 3) * 512 + d], wv, s3);
    }
    const float gc = g[c];
    const int sg = c >> 5, q2 = (c >> 3) & 3, jj = c & 7;
    const float sv[4] = {s0, s1, s2, s3};
    #pragma unroll
    for (int ii = 0; ii < 4; ++ii) {
      const int i = i0 + ii, it = i >> 4, m = i & 15;
      WovgB[((((it * 8 + sg) * 4 + q2) * 16) + m) * 8 + jj] = f2bf(sv[ii] * gc);
    }
  } else if (blk < 68) {
    const int b = blk - 64;
    __shared__ float qps[512];
    for (int d = tid; d < 512; d += 256) {
      float s = 0.f;
      #pragma unroll 16
      for (int cc = 0; cc < 256; ++cc)
        s = fmaf(Wq[d * 256 + cc], q[b * 256 + cc], s);
      qps[d] = s;
    }
    __syncthreads();
    const int c = tid;
    float s = 0.f;
    #pragma unroll 16
    for (int d = 0; d < 512; ++d)
      s = fmaf(Wkv[d * 256 + c], qps[d], s);
    gqk[b * 256 + c] = s * g[c] * 0.044194173824159216f;  // 512^-0.5
  }
}

// Pass 1: partial (ssq, dt) per (b,n,px) over a 64-channel quarter.
// 512 blocks x 256 thr (2 blocks/CU, 8 waves/CU); thread = 4 px (float4).
__global__ __launch_bounds__(256) void stats1_kernel(
    const float* __restrict__ cin, unsigned char* __restrict__ ws) {
  const float* gqk = (const float*)(ws + 131072);
  float2* part = (float2*)(ws + 135168);
  const int blk = blockIdx.x, tid = threadIdx.x;
  const int chs = blk & 3, pxt = (blk >> 2) & 3, n = (blk >> 4) & 7, b = blk >> 7;
  const int px = pxt * 1024 + tid * 4;
  const float* cp = cin + ((size_t)(b * 8 + n) * 256 + chs * 64) * 4096 + px;
  const float* gq = gqk + b * 256 + chs * 64;
  floatx4 ssq = {0.f, 0.f, 0.f, 0.f}, dt = {0.f, 0.f, 0.f, 0.f};
  #pragma unroll 8
  for (int ch = 0; ch < 64; ++ch) {
    const floatx4 v = *(const floatx4*)(cp + (size_t)ch * 4096);
    const float gg = gq[ch];                       // uniform -> s_load
    ssq += v * v;
    dt += v * gg;
  }
  float2* pp = part + ((size_t)((b * 8 + n) * 4 + chs)) * 4096 + px;
  const floatx4 o0 = {ssq[0], dt[0], ssq[1], dt[1]};
  const floatx4 o1 = {ssq[2], dt[2], ssq[3], dt[3]};
  *(floatx4*)pp = o0;
  *(floatx4*)(pp + 2) = o1;
}

// Pass 1b: combine quarters, exact softmax, final weights w = softmax * invr.
// 128 blocks x 128 thr, 1 px/thread; all traffic L2/L3-resident (~4.5 MB).
__global__ __launch_bounds__(128) void stats2_kernel(unsigned char* __restrict__ ws) {
  const float2* part = (const float2*)(ws + 135168);
  float* wout = (float*)(ws + 4329472);
  const int gid = blockIdx.x * 128 + threadIdx.x;   // 0..16383
  const int b = gid >> 12, px = gid & 4095;
  float dv[8], ir[8];
  #pragma unroll
  for (int n = 0; n < 8; ++n) {
    float ss = 0.f, dd = 0.f;
    #pragma unroll
    for (int chs = 0; chs < 4; ++chs) {
      const float2 pr = part[((size_t)((b * 8 + n) * 4 + chs)) * 4096 + px];
      ss += pr.x; dd += pr.y;
    }
    const float invr = rsqrtf(ss * (1.f / 256.f) + 1e-6f);
    ir[n] = invr;
    dv[n] = dd * invr;
  }
  float mx = dv[0];
  #pragma unroll
  for (int n = 1; n < 8; ++n) mx = fmaxf(mx, dv[n]);
  float e[8], Z = 0.f;
  #pragma unroll
  for (int n = 0; n < 8; ++n) { e[n] = __expf(dv[n] - mx); Z += e[n]; }
  const float iZ = 1.f / Z;
  float* wp = wout + ((size_t)(b * 4096 + px)) * 8;
  #pragma unroll
  for (int n = 0; n < 8; ++n) wp[n] = e[n] * iZ * ir[n];
}

// Pass 2: t accumulation. 512 blocks x 256 thr (2 blocks/CU, 8 waves/CU).
// Block = (b, 8-ch group, 1024-px tile); thread = 8 ch x 4 px (float4 loads,
// 1 KB/wave-instruction). t[8][4]+w[4][8] statically indexed, ~85 VGPR.
__global__ __launch_bounds__(256) void wsum_kernel(
    const float* __restrict__ cin, unsigned char* __restrict__ ws) {
  const float* wv = (const float*)(ws + 4329472);
  short8* tfrag = (short8*)(ws + 4853760);
  const int blk = blockIdx.x, tid = threadIdx.x;
  const int pxt = blk & 3, cg = (blk >> 2) & 31, b = blk >> 7;
  const int px = pxt * 1024 + tid * 4;

  float w[4][8];
  const float* wp = wv + ((size_t)(b * 4096 + px)) * 8;
  #pragma unroll
  for (int p = 0; p < 4; ++p) {
    const floatx4 a = *(const floatx4*)(wp + p * 8);
    const floatx4 bq = *(const floatx4*)(wp + p * 8 + 4);
    w[p][0] = a[0]; w[p][1] = a[1]; w[p][2] = a[2]; w[p][3] = a[3];
    w[p][4] = bq[0]; w[p][5] = bq[1]; w[p][6] = bq[2]; w[p][7] = bq[3];
  }

  float t[8][4];
  #pragma unroll
  for (int j = 0; j < 8; ++j)
    #pragma unroll
    for (int p = 0; p < 4; ++p) t[j][p] = 0.f;

  const float* cb = cin + ((size_t)(b * 8) * 256 + cg * 8) * 4096 + px;
  #pragma unroll
  for (int n = 0; n < 8; ++n) {
    const float* cp = cb + (size_t)n * 256 * 4096;
    #pragma unroll
    for (int j = 0; j < 8; ++j) {
      const floatx4 v = *(const floatx4*)(cp + (size_t)j * 4096);
      #pragma unroll
      for (int p = 0; p < 4; ++p) t[j][p] = fmaf(w[p][n], v[p], t[j][p]);
    }
  }

  // fragments: ch = cg*8 + j -> s = cg>>2, q = cg&3, jj = j; 64 B/thread.
  const int P = px >> 4, m = px & 15, s = cg >> 2, qq = cg & 3;
  short8* tp = tfrag + (((size_t)(b * 256 + P) * 8 + s) * 4 + qq) * 16 + m;
  #pragma unroll
  for (int p = 0; p < 4; ++p) {
    short8 pk;
    #pragma unroll
    for (int j = 0; j < 8; ++j) pk[j] = f2bf(t[j][p]);
    tp[p] = pk;
  }
}

// Pass 3: out[256 i][256 px] per block = Wovg(bf16) @ t(bf16) + bo.
// Block = (b, ig: 64 i-rows, pxg: 256 px). 256 blocks x 256 thr (4 waves).
__global__ __launch_bounds__(256, 2) void gemm_kernel(
    const float* __restrict__ bo, const unsigned char* __restrict__ ws,
    float* __restrict__ out) {
  const short8* Av = (const short8*)ws;
  const short8* Tv = (const short8*)(ws + 4853760);
  __shared__ short8 tBs[1024];   // 16 KB: t[32 ch][256 px] for current s
  const int blk = blockIdx.x, tid = threadIdx.x;
  const int b = blk >> 6, ig = (blk >> 4) & 3, pxg = blk & 15;
  const int lane = tid & 63, w = tid >> 6;
  const int it = ig * 4 + w;                  // wave -> 16 i-rows
  const int qf = lane >> 4, m = lane & 15;
  floatx4 acc[16];
  #pragma unroll
  for (int nt = 0; nt < 16; ++nt) acc[nt] = (floatx4){0.f, 0.f, 0.f, 0.f};
  #pragma unroll
  for (int s = 0; s < 8; ++s) {
    if (s) __syncthreads();                   // protect tBs reuse
    #pragma unroll
    for (int k = 0; k < 4; ++k) {             // stage 16 KB, coalesced 16 B/lane
      const int idx = tid + k * 256;
      const int nt = idx >> 6, r = idx & 63;
      tBs[idx] = Tv[(size_t)((b * 256 + pxg * 16 + nt) * 8 + s) * 64 + r];
    }
    __syncthreads();
    const short8 a = Av[((it * 8 + s) * 4 + qf) * 16 + m];
    #pragma unroll
    for (int nt = 0; nt < 16; ++nt)
      acc[nt] = __builtin_amdgcn_mfma_f32_16x16x32_bf16(a, tBs[nt * 64 + lane], acc[nt], 0, 0, 0);
  }
  // D layout: col = m (px), row = qf*4 + r (i)
  float* ob = out + (size_t)(b * 256) * 4096 + pxg * 256;
  #pragma unroll
  for (int nt = 0; nt < 16; ++nt)
    #pragma unroll
    for (int r = 0; r < 4; ++r) {
      const int i = it * 16 + qf * 4 + r;
      ob[(size_t)i * 4096 + nt * 16 + m] = acc[nt][r] + bo[i];
    }
}

extern "C" void kernel_launch(void* const* d_in, const int* in_sizes, int n_in,
                              void* d_out, int out_size, void* d_ws, size_t ws_size,
                              hipStream_t stream) {
  const float* q   = (const float*)d_in[0];
  const float* c   = (const float*)d_in[1];
  const float* g   = (const float*)d_in[2];
  const float* Wq  = (const float*)d_in[3];
  const float* Wkv = (const float*)d_in[4];
  const float* Wo  = (const float*)d_in[5];
  const float* bo  = (const float*)d_in[6];
  float* out = (float*)d_out;
  unsigned char* ws = (unsigned char*)d_ws;   // needs 13,242,368 bytes
  pre_kernel<<<68, 256, 0, stream>>>(q, g, Wq, Wkv, Wo, ws);
  stats1_kernel<<<512, 256, 0, stream>>>(c, ws);
  stats2_kernel<<<128, 128, 0, stream>>>(ws);
  wsum_kernel<<<512, 256, 0, stream>>>(c, ws);
  gemm_kernel<<<256, 256, 0, stream>>>(bo, ws, out);
}

// Round 4
// 282.049 us; speedup vs baseline: 1.0065x; 1.0065x over previous
//
#include <hip/hip_runtime.h>

// B=4, N=8, C=256, H=64, W=64, D=512 (single query per batch).
// Algebraic collapse: c is the only large tensor; K and V never formed.
//   gqk[b,c]  = g[c] * D^-0.5 * (Wkv_upper^T (Wq q_b))[c]
//   d[n,px]   = invr[n,px] * <c[b,n,:,px], gqk[b,:]>
//   w[n,px]   = softmax_n(d) * invr[n,px]
//   t[c,px]   = sum_n w[n,px] * c[b,n,c,px]
//   out       = Wovg @ t + bo,  Wovg = Wo @ Wkv_lower * diag(g)  (bf16 MFMA)
//
// R6: R5 proved 1 KB spans at 16 KB stride buy nothing (R5 == R4 + launch).
// The poison fills in the same profile stream 512 MiB at 6.9 TB/s -> the only
// proven-fast pattern is FULLY CONTIGUOUS. stats1 is restructured to read c
// sequentially (block = (b,n,32ch) streams its 512 KB row-after-row; each
// thread owns 8 fixed px in registers -> no LDS, no barrier). wsum keeps
// (ch,px)-indexed output (can't be fully contiguous) with 2 KB chunks.
// ws: [0,131072)         WovgB bf16, A-fragment-linear:
//                        (i,c) -> ((((i>>4)*8+(c>>5))*4+((c>>3)&3))*16+(i&15))*8+(c&7)
//     [131072,135168)    gqk f32 [4][256]
//     [135168,8523776)   partials float2[(b*8+n)*8+chs][4096 px] = (ssq,dt)
//     [8523776,9048064)  w f32 [4 b][4096 px][8 n]
//     [9048064,17436672) tfrag bf16: (b,P=px>>4,s,q,m=px&15,jj) ->
//                        short idx ((((b*256+P)*8+s)*4+q)*16+m)*8+jj

typedef __attribute__((ext_vector_type(8))) short short8;
typedef __attribute__((ext_vector_type(4))) float floatx4;

static __device__ __forceinline__ short f2bf(float f) {
  unsigned u = __float_as_uint(f);
  u += 0x7fffu + ((u >> 16) & 1u);   // round-to-nearest-even
  return (short)(u >> 16);
}

// blocks 0..63: Wovg rows 4i..4i+3 (Wkv_lower stays L2-hot across blocks)
// blocks 64..67: gqk for batch b
__global__ __launch_bounds__(256) void pre_kernel(
    const float* __restrict__ q, const float* __restrict__ g,
    const float* __restrict__ Wq, const float* __restrict__ Wkv,
    const float* __restrict__ Wo, unsigned char* __restrict__ ws) {
  short* WovgB = (short*)ws;
  float* gqk = (float*)(ws + 131072);
  const int blk = blockIdx.x, tid = threadIdx.x;
  if (blk < 64) {
    const int i0 = blk * 4, c = tid;
    float s0 = 0.f, s1 = 0.f, s2 = 0.f, s3 = 0.f;
    #pragma unroll 8
    for (int d = 0; d < 512; ++d) {
      const float wv = Wkv[(512 + d) * 256 + c];   // vector load
      s0 = fmaf(Wo[(i0 + 0) * 512 + d], wv, s0);   // Wo: uniform -> s_load
      s1 = fmaf(Wo[(i0 + 1) * 512 + d], wv, s1);
      s2 = fmaf(Wo[(i0 + 2) * 512 + d], wv, s2);
      s3 = fmaf(Wo[(i0 + 3) * 512 + d], wv, s3);
    }
    const float gc = g[c];
    const int sg = c >> 5, q2 = (c >> 3) & 3, jj = c & 7;
    const float sv[4] = {s0, s1, s2, s3};
    #pragma unroll
    for (int ii = 0; ii < 4; ++ii) {
      const int i = i0 + ii, it = i >> 4, m = i & 15;
      WovgB[((((it * 8 + sg) * 4 + q2) * 16) + m) * 8 + jj] = f2bf(sv[ii] * gc);
    }
  } else if (blk < 68) {
    const int b = blk - 64;
    __shared__ float qps[512];
    for (int d = tid; d < 512; d += 256) {
      float s = 0.f;
      #pragma unroll 16
      for (int cc = 0; cc < 256; ++cc)
        s = fmaf(Wq[d * 256 + cc], q[b * 256 + cc], s);
      qps[d] = s;
    }
    __syncthreads();
    const int c = tid;
    float s = 0.f;
    #pragma unroll 16
    for (int d = 0; d < 512; ++d)
      s = fmaf(Wkv[d * 256 + c], qps[d], s);
    gqk[b * 256 + c] = s * g[c] * 0.044194173824159216f;  // 512^-0.5
  }
}

// Pass 1: FULLY CONTIGUOUS c read. Block = (b, n, 32-ch slice) streams its
// 512 KB sequentially (each row: 4 waves x 2 x 1 KB float4 instrs cover the
// full 16 KB). Thread owns 8 fixed px in regs across all 32 rows. 256 blocks
// x 512 thr; ~40 VGPR; no LDS, no barrier.
__global__ __launch_bounds__(512) void stats1_kernel(
    const float* __restrict__ cin, unsigned char* __restrict__ ws) {
  const float* gqk = (const float*)(ws + 131072);
  float* part = (float*)(ws + 135168);
  const int blk = blockIdx.x, tid = threadIdx.x;
  const int chs = blk & 7, n = (blk >> 3) & 7, b = blk >> 6;
  const int px0 = tid * 4;                       // and px0 + 2048
  const float* base = cin + ((size_t)((b * 8 + n) * 256) + chs * 32) * 4096;
  const float* gqp = gqk + b * 256 + chs * 32;
  floatx4 s0 = {0.f,0.f,0.f,0.f}, d0 = {0.f,0.f,0.f,0.f};
  floatx4 s1 = {0.f,0.f,0.f,0.f}, d1 = {0.f,0.f,0.f,0.f};
  #pragma unroll 4
  for (int ch = 0; ch < 32; ++ch) {
    const float gg = gqp[ch];                    // uniform -> s_load
    const floatx4 v0 = *(const floatx4*)(base + (size_t)ch * 4096 + px0);
    const floatx4 v1 = *(const floatx4*)(base + (size_t)ch * 4096 + px0 + 2048);
    s0 += v0 * v0; d0 += v0 * gg;
    s1 += v1 * v1; d1 += v1 * gg;
  }
  // partials interleaved (ssq,dt) per px; 32 B/thread x2, contiguous spans
  float* pp = part + ((size_t)((b * 8 + n) * 8 + chs)) * 8192;
  const floatx4 o0 = {s0[0], d0[0], s0[1], d0[1]};
  const floatx4 o1 = {s0[2], d0[2], s0[3], d0[3]};
  const floatx4 o2 = {s1[0], d1[0], s1[1], d1[1]};
  const floatx4 o3 = {s1[2], d1[2], s1[3], d1[3]};
  *(floatx4*)(pp + (size_t)px0 * 2) = o0;
  *(floatx4*)(pp + (size_t)px0 * 2 + 4) = o1;
  *(floatx4*)(pp + (size_t)(px0 + 2048) * 2) = o2;
  *(floatx4*)(pp + (size_t)(px0 + 2048) * 2 + 4) = o3;
}

// Pass 1b: combine 8 ch-slices, exact softmax -> w = softmax*invr (512 KB).
// 64 blocks x 256 thr, 1 px/thread; all traffic L2/L3-resident (~8.5 MB).
__global__ __launch_bounds__(256) void stats2_kernel(unsigned char* __restrict__ ws) {
  const float* part = (const float*)(ws + 135168);
  float* wout = (float*)(ws + 8523776);
  const int gid = blockIdx.x * 256 + threadIdx.x;   // 0..16383
  const int b = gid >> 12, px = gid & 4095;
  float dv[8], ir[8];
  #pragma unroll
  for (int n = 0; n < 8; ++n) {
    float ss = 0.f, dd = 0.f;
    #pragma unroll
    for (int chs = 0; chs < 8; ++chs) {
      const float2 pr = *(const float2*)(part +
          ((size_t)((b * 8 + n) * 8 + chs)) * 8192 + px * 2);
      ss += pr.x; dd += pr.y;
    }
    const float invr = rsqrtf(ss * (1.f / 256.f) + 1e-6f);
    ir[n] = invr;
    dv[n] = dd * invr;
  }
  float mx = dv[0];
  #pragma unroll
  for (int n = 1; n < 8; ++n) mx = fmaxf(mx, dv[n]);
  float e[8], Z = 0.f;
  #pragma unroll
  for (int n = 0; n < 8; ++n) { e[n] = __expf(dv[n] - mx); Z += e[n]; }
  const float iZ = 1.f / Z;
  float* wp = wout + ((size_t)(b * 4096 + px)) * 8;
  #pragma unroll
  for (int n = 0; n < 8; ++n) wp[n] = e[n] * iZ * ir[n];
}

// Pass 2: t accumulation. Block = (b, 16-ch group, 512-px tile): each row
// contributes a 2 KB chunk (1 KB per wave-instr). 512 blocks x 512 thr
// (2 blocks/CU, 16 waves/CU). Thread = 4 ch x 4 px: t[4][4] + w[4][8],
// all statically indexed, ~90 VGPR under the 128 cap.
__global__ __launch_bounds__(512, 2) void wsum_kernel(
    const float* __restrict__ cin, unsigned char* __restrict__ ws) {
  const float* wv = (const float*)(ws + 8523776);
  short* tfragS = (short*)(ws + 9048064);
  const int blk = blockIdx.x, tid = threadIdx.x;
  const int pxt = blk & 7, cg = (blk >> 3) & 15, b = blk >> 7;
  const int pl = tid & 127, cs = tid >> 7;       // cs in 0..3
  const int px0 = pxt * 512 + pl * 4;

  float w[4][8];
  const float* wp = wv + ((size_t)(b * 4096 + px0)) * 8;
  #pragma unroll
  for (int p = 0; p < 4; ++p) {
    const floatx4 a = *(const floatx4*)(wp + p * 8);
    const floatx4 bq = *(const floatx4*)(wp + p * 8 + 4);
    w[p][0] = a[0]; w[p][1] = a[1]; w[p][2] = a[2]; w[p][3] = a[3];
    w[p][4] = bq[0]; w[p][5] = bq[1]; w[p][6] = bq[2]; w[p][7] = bq[3];
  }

  float t[4][4];
  #pragma unroll
  for (int ci = 0; ci < 4; ++ci)
    #pragma unroll
    for (int p = 0; p < 4; ++p) t[ci][p] = 0.f;

  const float* cb = cin + ((size_t)(b * 8) * 256 + cg * 16 + cs * 4) * 4096 + px0;
  #pragma unroll
  for (int n = 0; n < 8; ++n) {
    #pragma unroll
    for (int ci = 0; ci < 4; ++ci) {
      const floatx4 v = *(const floatx4*)(cb + (size_t)n * 256 * 4096
                                             + (size_t)ci * 4096);
      #pragma unroll
      for (int p = 0; p < 4; ++p) t[ci][p] = fmaf(w[p][n], v[p], t[ci][p]);
    }
  }

  // fragments: ch = cg*16 + cs*4 + ci -> s = cg>>1, q = (cg&1)*2 + (cs>>1),
  // jj = (cs&1)*4 + ci. px0..px0+3 share P; m = (px0&15)+p. short4 stores.
  const int P = px0 >> 4, mb = px0 & 15;
  const int s = cg >> 1, qq = (cg & 1) * 2 + (cs >> 1), jjb = (cs & 1) * 4;
  typedef __attribute__((ext_vector_type(4))) short short4v;
  #pragma unroll
  for (int p = 0; p < 4; ++p) {
    short4v pk;
    #pragma unroll
    for (int ci = 0; ci < 4; ++ci) pk[ci] = f2bf(t[ci][p]);
    *(short4v*)(tfragS +
        (size_t)(((((b * 256 + P) * 8 + s) * 4 + qq) * 16) + mb + p) * 8 + jjb) = pk;
  }
}

// Pass 3: out[256 i][256 px] per block = Wovg(bf16) @ t(bf16) + bo.
// Block = (b, ig: 64 i-rows, pxg: 256 px). 256 blocks x 256 thr (4 waves).
__global__ __launch_bounds__(256, 2) void gemm_kernel(
    const float* __restrict__ bo, const unsigned char* __restrict__ ws,
    float* __restrict__ out) {
  const short8* Av = (const short8*)ws;
  const short8* Tv = (const short8*)(ws + 9048064);
  __shared__ short8 tBs[1024];   // 16 KB: t[32 ch][256 px] for current s
  const int blk = blockIdx.x, tid = threadIdx.x;
  const int b = blk >> 6, ig = (blk >> 4) & 3, pxg = blk & 15;
  const int lane = tid & 63, w = tid >> 6;
  const int it = ig * 4 + w;                  // wave -> 16 i-rows
  const int qf = lane >> 4, m = lane & 15;
  floatx4 acc[16];
  #pragma unroll
  for (int nt = 0; nt < 16; ++nt) acc[nt] = (floatx4){0.f, 0.f, 0.f, 0.f};
  #pragma unroll
  for (int s = 0; s < 8; ++s) {
    if (s) __syncthreads();                   // protect tBs reuse
    #pragma unroll
    for (int k = 0; k < 4; ++k) {             // stage 16 KB, coalesced 16 B/lane
      const int idx = tid + k * 256;
      const int nt = idx >> 6, r = idx & 63;
      tBs[idx] = Tv[(size_t)((b * 256 + pxg * 16 + nt) * 8 + s) * 64 + r];
    }
    __syncthreads();
    const short8 a = Av[((it * 8 + s) * 4 + qf) * 16 + m];
    #pragma unroll
    for (int nt = 0; nt < 16; ++nt)
      acc[nt] = __builtin_amdgcn_mfma_f32_16x16x32_bf16(a, tBs[nt * 64 + lane], acc[nt], 0, 0, 0);
  }
  // D layout: col = m (px), row = qf*4 + r (i)
  float* ob = out + (size_t)(b * 256) * 4096 + pxg * 256;
  #pragma unroll
  for (int nt = 0; nt < 16; ++nt)
    #pragma unroll
    for (int r = 0; r < 4; ++r) {
      const int i = it * 16 + qf * 4 + r;
      ob[(size_t)i * 4096 + nt * 16 + m] = acc[nt][r] + bo[i];
    }
}

extern "C" void kernel_launch(void* const* d_in, const int* in_sizes, int n_in,
                              void* d_out, int out_size, void* d_ws, size_t ws_size,
                              hipStream_t stream) {
  const float* q   = (const float*)d_in[0];
  const float* c   = (const float*)d_in[1];
  const float* g   = (const float*)d_in[2];
  const float* Wq  = (const float*)d_in[3];
  const float* Wkv = (const float*)d_in[4];
  const float* Wo  = (const float*)d_in[5];
  const float* bo  = (const float*)d_in[6];
  float* out = (float*)d_out;
  unsigned char* ws = (unsigned char*)d_ws;   // needs 17,436,672 bytes
  pre_kernel<<<68, 256, 0, stream>>>(q, g, Wq, Wkv, Wo, ws);
  stats1_kernel<<<256, 512, 0, stream>>>(c, ws);
  stats2_kernel<<<64, 256, 0, stream>>>(ws);
  wsum_kernel<<<512, 512, 0, stream>>>(c, ws);
  gemm_kernel<<<256, 256, 0, stream>>>(bo, ws, out);
}

// Round 5
// 249.116 us; speedup vs baseline: 1.1395x; 1.1322x over previous
//
#include <hip/hip_runtime.h>

// B=4, N=8, C=256, H=64, W=64, D=512 (single query per batch).
// Algebraic collapse: c is read exactly once; K and V never formed.
//   gqk[b,c]  = g[c] * D^-0.5 * (Wkv_upper^T (Wq q_b))[c]
//   dots[n]   = inv_rms[n,px] * <c[b,n,:,px], gqk[b,:]>
//   t[c,px]   = sum_n softmax_n * inv_rms * c[b,n,c,px]
//   out       = Wovg @ t + bo,  Wovg = Wo @ Wkv_lower * diag(g)  (bf16 MFMA)
//
// R7: back to the single-pass structure (R2: 145 MB traffic, 63 us @ 2.33
// TB/s with 128 B spans). The 2-pass experiments (R4-R6) proved strided
// chunked reads run ~3-3.5 TB/s, so the win is a bigger px tile, not more
// passes. This kernel: block = (b,h) full 64-px row -> 256 B spans/row,
// 512 thr, thread = 8 ch x 4 px (t[8][4]+vals[8]x4 ~ 110 VGPR).
// __launch_bounds__(512,2): 256-VGPR cap -- grid is 1 block/CU, so there is
// nothing to gain from squeezing (R3's 64-reg spill disaster is excluded by
// construction). One barrier per token (double-buffered LDS partials).

typedef __attribute__((ext_vector_type(8))) short short8;
typedef __attribute__((ext_vector_type(4))) float floatx4;

static __device__ __forceinline__ short f2bf(float f) {
  unsigned u = __float_as_uint(f);
  u += 0x7fffu + ((u >> 16) & 1u);   // round-to-nearest-even
  return (short)(u >> 16);
}

// ws: [0,131072) WovgB bf16, A-fragment-linear: element (i,c) at short index
//     ((((i>>4)*8 + (c>>5))*4 + ((c>>3)&3))*16 + (i&15))*8 + (c&7)
//     [131072,135168) gqk f32 [4][256]
// blocks 0..63: Wovg rows 4i..4i+3; blocks 64..67: gqk for batch b
__global__ __launch_bounds__(256) void pre_kernel(
    const float* __restrict__ q, const float* __restrict__ g,
    const float* __restrict__ Wq, const float* __restrict__ Wkv,
    const float* __restrict__ Wo, unsigned char* __restrict__ ws) {
  short* WovgB = (short*)ws;
  float* gqk = (float*)(ws + 131072);
  const int blk = blockIdx.x, tid = threadIdx.x;
  if (blk < 64) {
    const int i0 = blk * 4, c = tid;
    float s0 = 0.f, s1 = 0.f, s2 = 0.f, s3 = 0.f;
    #pragma unroll 8
    for (int d = 0; d < 512; ++d) {
      const float wv = Wkv[(512 + d) * 256 + c];   // vector load
      s0 = fmaf(Wo[(i0 + 0) * 512 + d], wv, s0);   // Wo: uniform -> s_load
      s1 = fmaf(Wo[(i0 + 1) * 512 + d], wv, s1);
      s2 = fmaf(Wo[(i0 + 2) * 512 + d], wv, s2);
      s3 = fmaf(Wo[(i0 + 3) * 512 + d], wv, s3);
    }
    const float gc = g[c];
    const int sg = c >> 5, q2 = (c >> 3) & 3, jj = c & 7;
    const float sv[4] = {s0, s1, s2, s3};
    #pragma unroll
    for (int ii = 0; ii < 4; ++ii) {
      const int i = i0 + ii, it = i >> 4, m = i & 15;
      WovgB[((((it * 8 + sg) * 4 + q2) * 16) + m) * 8 + jj] = f2bf(sv[ii] * gc);
    }
  } else if (blk < 68) {
    const int b = blk - 64;
    __shared__ float qps[512];
    for (int d = tid; d < 512; d += 256) {
      float s = 0.f;
      #pragma unroll 16
      for (int cc = 0; cc < 256; ++cc)
        s = fmaf(Wq[d * 256 + cc], q[b * 256 + cc], s);
      qps[d] = s;
    }
    __syncthreads();
    const int c = tid;
    float s = 0.f;
    #pragma unroll 16
    for (int d = 0; d < 512; ++d)
      s = fmaf(Wkv[d * 256 + c], qps[d], s);
    gqk[b * 256 + c] = s * g[c] * 0.044194173824159216f;  // 512^-0.5
  }
}

// Block = (b, h): full 64-px row, 512 thr = 8 waves, 256 blocks (1/CU).
// Thread: cgrp = tid>>4 owns ch [cgrp*8, cgrp*8+8); pgrp = tid&15 owns
// px [pgrp*4, pgrp*4+4) via float4 -> 16 consecutive lanes = 256 B span.
__global__ __launch_bounds__(512, 2) void attn_kernel(
    const float* __restrict__ cin, const float* __restrict__ bo,
    const unsigned char* __restrict__ ws, float* __restrict__ out) {
  const short8* Av = (const short8*)ws;
  const float* gqk = (const float*)(ws + 131072);
  const int blk = blockIdx.x;                 // 256 blocks = b*64 + h
  const int b = blk >> 6, h = blk & 63;
  const int tid = threadIdx.x;
  const int lane = tid & 63, w = tid >> 6;    // w in 0..7
  const int cgrp = tid >> 4;                  // 0..31
  const int pgrp = tid & 15;                  // px0 = pgrp*4

  __shared__ short tB[8][4][64][8];           // 32 KB, B-fragment-linear
  __shared__ float redS[2][8][16][4], redD[2][8][16][4];   // 8 KB

  float rg[8];
  #pragma unroll
  for (int j = 0; j < 8; ++j) rg[j] = gqk[b * 256 + cgrp * 8 + j];

  float t[8][4];
  #pragma unroll
  for (int j = 0; j < 8; ++j)
    #pragma unroll
    for (int p = 0; p < 4; ++p) t[j][p] = 0.f;
  float mM[4], zZ[4];
  #pragma unroll
  for (int p = 0; p < 4; ++p) { mM[p] = -1e30f; zZ[p] = 0.f; }

  const float* cb = cin + ((size_t)(b * 8) * 256 + cgrp * 8) * 4096
                        + h * 64 + pgrp * 4;
  for (int n = 0; n < 8; ++n) {
    const float* cp = cb + (size_t)n * 256 * 4096;
    floatx4 vals[8];
    #pragma unroll
    for (int j = 0; j < 8; ++j)
      vals[j] = *(const floatx4*)(cp + (size_t)j * 4096);
    float ssq[4] = {0.f, 0.f, 0.f, 0.f}, dt[4] = {0.f, 0.f, 0.f, 0.f};
    #pragma unroll
    for (int j = 0; j < 8; ++j)
      #pragma unroll
      for (int p = 0; p < 4; ++p) {
        ssq[p] = fmaf(vals[j][p], vals[j][p], ssq[p]);
        dt[p] = fmaf(vals[j][p], rg[j], dt[p]);
      }
    // combine the wave's 4 cgrp sub-groups (lane bits 4,5)
    #pragma unroll
    for (int p = 0; p < 4; ++p) {
      ssq[p] += __shfl_xor(ssq[p], 16);
      ssq[p] += __shfl_xor(ssq[p], 32);
      dt[p] += __shfl_xor(dt[p], 16);
      dt[p] += __shfl_xor(dt[p], 32);
    }
    if ((lane >> 4) == 0) {
      #pragma unroll
      for (int p = 0; p < 4; ++p) {
        redS[n & 1][w][pgrp][p] = ssq[p];
        redD[n & 1][w][pgrp][p] = dt[p];
      }
    }
    __syncthreads();                          // the only barrier per token
    floatx4 S = {0.f, 0.f, 0.f, 0.f}, Dt = {0.f, 0.f, 0.f, 0.f};
    #pragma unroll
    for (int ww = 0; ww < 8; ++ww) {
      S += *(const floatx4*)(&redS[n & 1][ww][pgrp][0]);
      Dt += *(const floatx4*)(&redD[n & 1][ww][pgrp][0]);
    }
    float wn[4], al[4];
    #pragma unroll
    for (int p = 0; p < 4; ++p) {
      const float invr = rsqrtf(S[p] * (1.f / 256.f) + 1e-6f);
      const float d = Dt[p] * invr;
      const float mn = fmaxf(mM[p], d);
      al[p] = __expf(mM[p] - mn);             // 0 on first token
      const float e = __expf(d - mn);
      zZ[p] = zZ[p] * al[p] + e;
      mM[p] = mn;
      wn[p] = e * invr;
    }
    #pragma unroll
    for (int j = 0; j < 8; ++j)
      #pragma unroll
      for (int p = 0; p < 4; ++p)
        t[j][p] = fmaf(wn[p], vals[j][p], t[j][p] * al[p]);
  }

  // write normalized t (bf16) in B-fragment order:
  // reader lane L=(q*16+m) of (s,nt) wants ch=s*32+q*8+jj, px=nt*16+m.
  // writer: ch = cgrp*8+j -> s = cgrp>>2, q = cgrp&3; px = pgrp*4+p ->
  // nt = pgrp>>2, m = (pgrp&3)*4+p. Thread owns all 8 jj -> short8 stores.
  {
    const int s = cgrp >> 2, qq = cgrp & 3;
    const int nt = pgrp >> 2, mb = (pgrp & 3) * 4;
    #pragma unroll
    for (int p = 0; p < 4; ++p) {
      const float invZ = 1.f / zZ[p];
      short8 pk;
      #pragma unroll
      for (int j = 0; j < 8; ++j) pk[j] = f2bf(t[j][p] * invZ);
      *(short8*)(&tB[s][nt][qq * 16 + mb + p][0]) = pk;
    }
  }
  __syncthreads();

  // phase 3: out[256 i][64 px] = Wovg(bf16) @ t(bf16); wave w -> 32 i-rows
  const int qf = lane >> 4, m = lane & 15;
  floatx4 acc[2][4];
  #pragma unroll
  for (int mt = 0; mt < 2; ++mt)
    #pragma unroll
    for (int nt = 0; nt < 4; ++nt) acc[mt][nt] = (floatx4){0.f, 0.f, 0.f, 0.f};
  #pragma unroll
  for (int s = 0; s < 8; ++s) {
    short8 a[2];
    #pragma unroll
    for (int mt = 0; mt < 2; ++mt)            // coalesced: 16 B/lane
      a[mt] = Av[(((w * 2 + mt) * 8 + s) * 4 + qf) * 16 + m];
    #pragma unroll
    for (int nt = 0; nt < 4; ++nt) {
      const short8 bf = *(const short8*)(&tB[s][nt][lane][0]);
      #pragma unroll
      for (int mt = 0; mt < 2; ++mt)
        acc[mt][nt] = __builtin_amdgcn_mfma_f32_16x16x32_bf16(a[mt], bf, acc[mt][nt], 0, 0, 0);
    }
  }
  // epilogue: D layout col=lane&15(px), row=qf*4+r(i)
  float* ob = out + (size_t)b * 256 * 4096 + h * 64;
  #pragma unroll
  for (int mt = 0; mt < 2; ++mt) {
    float bov[4];
    #pragma unroll
    for (int r = 0; r < 4; ++r) bov[r] = bo[(w * 2 + mt) * 16 + qf * 4 + r];
    #pragma unroll
    for (int nt = 0; nt < 4; ++nt)
      #pragma unroll
      for (int r = 0; r < 4; ++r) {
        const int i = (w * 2 + mt) * 16 + qf * 4 + r;
        ob[(size_t)i * 4096 + nt * 16 + m] = acc[mt][nt][r] + bov[r];
      }
  }
}

extern "C" void kernel_launch(void* const* d_in, const int* in_sizes, int n_in,
                              void* d_out, int out_size, void* d_ws, size_t ws_size,
                              hipStream_t stream) {
  const float* q   = (const float*)d_in[0];
  const float* c   = (const float*)d_in[1];
  const float* g   = (const float*)d_in[2];
  const float* Wq  = (const float*)d_in[3];
  const float* Wkv = (const float*)d_in[4];
  const float* Wo  = (const float*)d_in[5];
  const float* bo  = (const float*)d_in[6];
  float* out = (float*)d_out;
  unsigned char* ws = (unsigned char*)d_ws;   // needs 135168 bytes
  pre_kernel<<<68, 256, 0, stream>>>(q, g, Wq, Wkv, Wo, ws);
  attn_kernel<<<256, 512, 0, stream>>>(c, bo, ws, out);
}